// Round 1
// baseline (12284.091 us; speedup 1.0000x reference)
//
#include <hip/hip_runtime.h>

#define N_NODES 50000
#define E_EDGES 1600000
#define E2 (E_EDGES + N_NODES)   // 1,650,000 with self loops
#define HEADS 4
#define CH 64
#define F 256
#define OUTC 10
#define BN_EPS 1e-5f
#define NEG_SLOPE 0.2f

// ---------------- GEMM + attention-coefficient kernel ----------------
// XW = X @ W  ([N,K] @ [K,256]); also S[n,h] = sum_c XW[n,h*64+c]*a_src[h*64+c],
// D likewise. One block = 8 rows, thread t = output column t, head = t/64.
template<int K, int RPB, int KT>
__global__ __launch_bounds__(256) void gemm_sd(
    const float* __restrict__ X, const float* __restrict__ W,
    const float* __restrict__ a_src, const float* __restrict__ a_dst,
    float* __restrict__ XW, float* __restrict__ S, float* __restrict__ D)
{
    __shared__ float xs[RPB][K];
    __shared__ float wls[KT][F];
    const int t = threadIdx.x;
    const int row0 = blockIdx.x * RPB;

    for (int i = t; i < RPB * K; i += 256) {
        int r = i / K, k = i % K;
        int n = row0 + r;
        xs[r][k] = (n < N_NODES) ? X[(size_t)n * K + k] : 0.f;
    }

    float acc[RPB];
#pragma unroll
    for (int r = 0; r < RPB; r++) acc[r] = 0.f;

    for (int k0 = 0; k0 < K; k0 += KT) {
        __syncthreads();
        for (int i = t; i < KT * F; i += 256) {
            int kk = i / F, c = i % F;
            wls[kk][c] = W[(size_t)(k0 + kk) * F + c];
        }
        __syncthreads();
#pragma unroll
        for (int kk = 0; kk < KT; kk++) {
            float wv = wls[kk][t];
#pragma unroll
            for (int r = 0; r < RPB; r++)
                acc[r] += xs[r][k0 + kk] * wv;
        }
    }

    const int lane = t & 63;
    const int head = t >> 6;
    const float as = a_src[t];   // a_src flat [H*C]; t = h*64+c
    const float ad = a_dst[t];

#pragma unroll
    for (int r = 0; r < RPB; r++) {
        int n = row0 + r;
        if (n < N_NODES) XW[(size_t)n * F + t] = acc[r];
        float ps = acc[r] * as;
        float pd = acc[r] * ad;
#pragma unroll
        for (int off = 32; off > 0; off >>= 1) {
            ps += __shfl_xor(ps, off, 64);
            pd += __shfl_xor(pd, off, 64);
        }
        if (lane == 0 && n < N_NODES) {
            S[n * HEADS + head] = ps;
            D[n * HEADS + head] = pd;
        }
    }
}

// ---------------- edge pass 1: softmax denominators ----------------
// Softmax is shift-invariant; logits are O(1) so we skip segment_max.
__global__ __launch_bounds__(256) void edge_denom(
    const int* __restrict__ eidx, const float* __restrict__ S,
    const float* __restrict__ D, float* __restrict__ denom)
{
    int e = blockIdx.x * blockDim.x + threadIdx.x;
    if (e >= E2) return;
    int src, dst;
    if (e < E_EDGES) { src = eidx[e]; dst = eidx[E_EDGES + e]; }
    else             { src = dst = e - E_EDGES; }
#pragma unroll
    for (int h = 0; h < HEADS; h++) {
        float z = S[src * HEADS + h] + D[dst * HEADS + h];
        float a = z > 0.f ? z : NEG_SLOPE * z;
        atomicAdd(&denom[dst * HEADS + h], __expf(a));
    }
}

// ---------------- edge pass 2: weighted scatter-add ----------------
// One 64-lane wave per edge; lane handles 4 consecutive channels (float4).
__global__ __launch_bounds__(256) void edge_agg(
    const int* __restrict__ eidx, const float* __restrict__ S,
    const float* __restrict__ D, const float* __restrict__ denom,
    const float* __restrict__ XW, float* __restrict__ Hb)
{
    int wave = (blockIdx.x * blockDim.x + threadIdx.x) >> 6;
    int lane = threadIdx.x & 63;
    if (wave >= E2) return;
    int src, dst;
    if (wave < E_EDGES) { src = eidx[wave]; dst = eidx[E_EDGES + wave]; }
    else                { src = dst = wave - E_EDGES; }
    int h = lane >> 4;  // channel block lane*4 .. lane*4+3 belongs to head (lane*4)/64
    float z = S[src * HEADS + h] + D[dst * HEADS + h];
    float a = z > 0.f ? z : NEG_SLOPE * z;
    float w = __expf(a) / (denom[dst * HEADS + h] + 1e-16f);

    const float4 xv = *reinterpret_cast<const float4*>(XW + (size_t)src * F + lane * 4);
    float* o = Hb + (size_t)dst * F + lane * 4;
    atomicAdd(o + 0, xv.x * w);
    atomicAdd(o + 1, xv.y * w);
    atomicAdd(o + 2, xv.z * w);
    atomicAdd(o + 3, xv.w * w);
}

// ---------------- bias + ReLU + per-channel batch stats ----------------
__global__ __launch_bounds__(256) void bias_relu_stats(
    float* __restrict__ Hb, const float* __restrict__ bias,
    float* __restrict__ stats)
{
    const int t = threadIdx.x;           // channel
    const float b = bias[t];
    float s = 0.f, sq = 0.f;
    for (int n = blockIdx.x; n < N_NODES; n += gridDim.x) {
        float v = Hb[(size_t)n * F + t] + b;
        v = v > 0.f ? v : 0.f;
        Hb[(size_t)n * F + t] = v;
        s += v; sq += v * v;
    }
    atomicAdd(&stats[t], s);
    atomicAdd(&stats[F + t], sq);
}

// ---------------- batchnorm apply ----------------
__global__ __launch_bounds__(256) void bn_apply(
    float* __restrict__ Hb, const float* __restrict__ stats,
    const float* __restrict__ gamma, const float* __restrict__ beta)
{
    const int t = threadIdx.x;
    const float inv_n = 1.f / (float)N_NODES;
    float mu = stats[t] * inv_n;
    float var = stats[F + t] * inv_n - mu * mu;
    float sc = rsqrtf(var + BN_EPS) * gamma[t];
    float sh = beta[t] - mu * sc;
    for (int n = blockIdx.x; n < N_NODES; n += gridDim.x)
        Hb[(size_t)n * F + t] = Hb[(size_t)n * F + t] * sc + sh;
}

// ---------------- classifier: [N,256] @ [256,10] + bc ----------------
__global__ __launch_bounds__(256) void classifier(
    const float* __restrict__ Hb, const float* __restrict__ Wc,
    const float* __restrict__ bc, float* __restrict__ out)
{
    __shared__ float wls[F][OUTC + 1];
    const int t = threadIdx.x;
    for (int i = t; i < F * OUTC; i += 256)
        wls[i / OUTC][i % OUTC] = Wc[i];
    __syncthreads();

    const int wave = t >> 6, lane = t & 63;
    const int n = blockIdx.x * 4 + wave;
    if (n >= N_NODES) return;

    float v[4];
#pragma unroll
    for (int j = 0; j < 4; j++)
        v[j] = Hb[(size_t)n * F + j * 64 + lane];

    float acc[OUTC];
#pragma unroll
    for (int o = 0; o < OUTC; o++) acc[o] = 0.f;
#pragma unroll
    for (int j = 0; j < 4; j++)
#pragma unroll
        for (int o = 0; o < OUTC; o++)
            acc[o] += v[j] * wls[j * 64 + lane][o];

#pragma unroll
    for (int off = 32; off > 0; off >>= 1)
#pragma unroll
        for (int o = 0; o < OUTC; o++)
            acc[o] += __shfl_xor(acc[o], off, 64);

    if (lane == 0) {
#pragma unroll
        for (int o = 0; o < OUTC; o++)
            out[(size_t)n * OUTC + o] = acc[o] + bc[o];
    }
}

extern "C" void kernel_launch(void* const* d_in, const int* in_sizes, int n_in,
                              void* d_out, int out_size, void* d_ws, size_t ws_size,
                              hipStream_t stream)
{
    const float* x   = (const float*)d_in[0];
    const int*   ei  = (const int*)d_in[1];
    const float* W1  = (const float*)d_in[2];
    const float* as1 = (const float*)d_in[3];
    const float* ad1 = (const float*)d_in[4];
    const float* b1  = (const float*)d_in[5];
    const float* W2  = (const float*)d_in[6];
    const float* as2 = (const float*)d_in[7];
    const float* ad2 = (const float*)d_in[8];
    const float* b2  = (const float*)d_in[9];
    const float* g1  = (const float*)d_in[10];
    const float* be1 = (const float*)d_in[11];
    const float* g2  = (const float*)d_in[12];
    const float* be2 = (const float*)d_in[13];
    const float* Wc  = (const float*)d_in[14];
    const float* bc  = (const float*)d_in[15];
    float* out = (float*)d_out;

    float* ws  = (float*)d_ws;
    float* xw  = ws;                              // N*F
    float* hb  = xw + (size_t)N_NODES * F;        // N*F
    float* Sv  = hb + (size_t)N_NODES * F;        // N*H
    float* Dv  = Sv + (size_t)N_NODES * HEADS;    // N*H
    float* dn  = Dv + (size_t)N_NODES * HEADS;    // N*H
    float* st  = dn + (size_t)N_NODES * HEADS;    // 2*F

    const int grid_e  = (E2 + 255) / 256;
    const int grid_ag = (E2 + 3) / 4;

    // ---- layer 1 ----
    gemm_sd<128, 8, 32><<<N_NODES / 8, 256, 0, stream>>>(x, W1, as1, ad1, xw, Sv, Dv);
    hipMemsetAsync(dn, 0, (size_t)N_NODES * HEADS * 4, stream);
    hipMemsetAsync(hb, 0, (size_t)N_NODES * F * 4, stream);
    edge_denom<<<grid_e, 256, 0, stream>>>(ei, Sv, Dv, dn);
    edge_agg<<<grid_ag, 256, 0, stream>>>(ei, Sv, Dv, dn, xw, hb);
    hipMemsetAsync(st, 0, 2 * F * 4, stream);
    bias_relu_stats<<<512, 256, 0, stream>>>(hb, b1, st);
    bn_apply<<<512, 256, 0, stream>>>(hb, st, g1, be1);

    // ---- layer 2 ----
    gemm_sd<256, 8, 32><<<N_NODES / 8, 256, 0, stream>>>(hb, W2, as2, ad2, xw, Sv, Dv);
    hipMemsetAsync(dn, 0, (size_t)N_NODES * HEADS * 4, stream);
    hipMemsetAsync(hb, 0, (size_t)N_NODES * F * 4, stream);
    edge_denom<<<grid_e, 256, 0, stream>>>(ei, Sv, Dv, dn);
    edge_agg<<<grid_ag, 256, 0, stream>>>(ei, Sv, Dv, dn, xw, hb);
    hipMemsetAsync(st, 0, 2 * F * 4, stream);
    bias_relu_stats<<<512, 256, 0, stream>>>(hb, b2, st);
    bn_apply<<<512, 256, 0, stream>>>(hb, st, g2, be2);

    // ---- classifier ----
    classifier<<<(N_NODES + 3) / 4, 256, 0, stream>>>(hb, Wc, bc, out);
}

// Round 2
// 1384.974 us; speedup vs baseline: 8.8695x; 8.8695x over previous
//
#include <hip/hip_runtime.h>

#define N_NODES 50000
#define E_EDGES 1600000
#define E2 (E_EDGES + N_NODES)   // 1,650,000 with self loops
#define HEADS 4
#define CH 64
#define F 256
#define OUTC 10
#define BN_EPS 1e-5f
#define NEG_SLOPE 0.2f
#define SCAN_T 1024
#define SCAN_CHUNK ((N_NODES + SCAN_T - 1) / SCAN_T)   // 49

// ---------------- GEMM + attention-coefficient kernel ----------------
template<int K, int RPB, int KT>
__global__ __launch_bounds__(256) void gemm_sd(
    const float* __restrict__ X, const float* __restrict__ W,
    const float* __restrict__ a_src, const float* __restrict__ a_dst,
    float* __restrict__ XW, float* __restrict__ S, float* __restrict__ D)
{
    __shared__ float xs[RPB][K];
    __shared__ float wls[KT][F];
    const int t = threadIdx.x;
    const int row0 = blockIdx.x * RPB;

    for (int i = t; i < RPB * K; i += 256) {
        int r = i / K, k = i % K;
        int n = row0 + r;
        xs[r][k] = (n < N_NODES) ? X[(size_t)n * K + k] : 0.f;
    }

    float acc[RPB];
#pragma unroll
    for (int r = 0; r < RPB; r++) acc[r] = 0.f;

    for (int k0 = 0; k0 < K; k0 += KT) {
        __syncthreads();
        for (int i = t; i < KT * F; i += 256) {
            int kk = i / F, c = i % F;
            wls[kk][c] = W[(size_t)(k0 + kk) * F + c];
        }
        __syncthreads();
#pragma unroll
        for (int kk = 0; kk < KT; kk++) {
            float wv = wls[kk][t];
#pragma unroll
            for (int r = 0; r < RPB; r++)
                acc[r] += xs[r][k0 + kk] * wv;
        }
    }

    const int lane = t & 63;
    const int head = t >> 6;
    const float as = a_src[t];
    const float ad = a_dst[t];

#pragma unroll
    for (int r = 0; r < RPB; r++) {
        int n = row0 + r;
        if (n < N_NODES) XW[(size_t)n * F + t] = acc[r];
        float ps = acc[r] * as;
        float pd = acc[r] * ad;
#pragma unroll
        for (int off = 32; off > 0; off >>= 1) {
            ps += __shfl_xor(ps, off, 64);
            pd += __shfl_xor(pd, off, 64);
        }
        if (lane == 0 && n < N_NODES) {
            S[n * HEADS + head] = ps;
            D[n * HEADS + head] = pd;
        }
    }
}

// ---------------- CSR build ----------------
__global__ __launch_bounds__(256) void count_deg(
    const int* __restrict__ eidx, int* __restrict__ deg)
{
    int e = blockIdx.x * blockDim.x + threadIdx.x;
    if (e >= E2) return;
    int dst = (e < E_EDGES) ? eidx[E_EDGES + e] : e - E_EDGES;
    atomicAdd(&deg[dst], 1);
}

__global__ __launch_bounds__(SCAN_T) void scan_deg(
    const int* __restrict__ deg, int* __restrict__ rowptr)
{
    __shared__ int part[SCAN_T];
    const int t = threadIdx.x;
    const int base = t * SCAN_CHUNK;
    int s = 0;
    for (int i = 0; i < SCAN_CHUNK; i++) {
        int idx = base + i;
        if (idx < N_NODES) s += deg[idx];
    }
    part[t] = s;
    __syncthreads();
    for (int off = 1; off < SCAN_T; off <<= 1) {
        int v = (t >= off) ? part[t - off] : 0;
        __syncthreads();
        part[t] += v;
        __syncthreads();
    }
    int run = (t == 0) ? 0 : part[t - 1];
    for (int i = 0; i < SCAN_CHUNK; i++) {
        int idx = base + i;
        if (idx < N_NODES) { rowptr[idx] = run; run += deg[idx]; }
    }
    if (t == 0) rowptr[N_NODES] = part[SCAN_T - 1];
}

__global__ __launch_bounds__(256) void scatter_edges(
    const int* __restrict__ eidx, const int* __restrict__ rowptr,
    int* __restrict__ cursor, int* __restrict__ esrc)
{
    int e = blockIdx.x * blockDim.x + threadIdx.x;
    if (e >= E2) return;
    int src, dst;
    if (e < E_EDGES) { src = eidx[e]; dst = eidx[E_EDGES + e]; }
    else             { src = dst = e - E_EDGES; }
    int pos = atomicAdd(&cursor[dst], 1);
    esrc[rowptr[dst] + pos] = src;
}

// ---------------- fused softmax + aggregation (gather, no atomics) ----
// One 64-lane wave per dst node. out[dst] = sum_e exp(a_e)*xw[src_e] / sum_e exp(a_e)
__global__ __launch_bounds__(256) void gat_aggregate(
    const int* __restrict__ rowptr, const int* __restrict__ esrc,
    const float* __restrict__ S, const float* __restrict__ D,
    const float* __restrict__ XW, float* __restrict__ Hb)
{
    const int wave = (blockIdx.x * blockDim.x + threadIdx.x) >> 6;
    const int lane = threadIdx.x & 63;
    if (wave >= N_NODES) return;
    const int dst = wave;
    const int beg = rowptr[dst], end = rowptr[dst + 1];
    const int h = lane >> 4;
    const float dh = D[dst * HEADS + h];

    float ax = 0.f, ay = 0.f, az = 0.f, aw = 0.f, den = 0.f;

    for (int i = beg; i < end; i += 64) {
        const int nb = min(64, end - i);
        int mysrc = (i + lane < end) ? esrc[i + lane] : 0;
        for (int j = 0; j < nb; j++) {
            int src = __shfl(mysrc, j, 64);
            float z = S[src * HEADS + h] + dh;
            float a = z > 0.f ? z : NEG_SLOPE * z;
            float w = __expf(a);
            const float4 xv = *reinterpret_cast<const float4*>(
                XW + (size_t)src * F + lane * 4);
            ax += w * xv.x; ay += w * xv.y; az += w * xv.z; aw += w * xv.w;
            den += w;
        }
    }
    const float inv = 1.f / (den + 1e-16f);
    float4 r = { ax * inv, ay * inv, az * inv, aw * inv };
    *reinterpret_cast<float4*>(Hb + (size_t)dst * F + lane * 4) = r;
}

// ---------------- bias + ReLU + per-channel batch stats ----------------
__global__ __launch_bounds__(256) void bias_relu_stats(
    float* __restrict__ Hb, const float* __restrict__ bias,
    float* __restrict__ stats)
{
    const int t = threadIdx.x;
    const float b = bias[t];
    float s = 0.f, sq = 0.f;
    for (int n = blockIdx.x; n < N_NODES; n += gridDim.x) {
        float v = Hb[(size_t)n * F + t] + b;
        v = v > 0.f ? v : 0.f;
        Hb[(size_t)n * F + t] = v;
        s += v; sq += v * v;
    }
    atomicAdd(&stats[t], s);
    atomicAdd(&stats[F + t], sq);
}

// ---------------- batchnorm apply ----------------
__global__ __launch_bounds__(256) void bn_apply(
    float* __restrict__ Hb, const float* __restrict__ stats,
    const float* __restrict__ gamma, const float* __restrict__ beta)
{
    const int t = threadIdx.x;
    const float inv_n = 1.f / (float)N_NODES;
    float mu = stats[t] * inv_n;
    float var = stats[F + t] * inv_n - mu * mu;
    float sc = rsqrtf(var + BN_EPS) * gamma[t];
    float sh = beta[t] - mu * sc;
    for (int n = blockIdx.x; n < N_NODES; n += gridDim.x)
        Hb[(size_t)n * F + t] = Hb[(size_t)n * F + t] * sc + sh;
}

// ---------------- classifier: [N,256] @ [256,10] + bc ----------------
__global__ __launch_bounds__(256) void classifier(
    const float* __restrict__ Hb, const float* __restrict__ Wc,
    const float* __restrict__ bc, float* __restrict__ out)
{
    __shared__ float wls[F][OUTC + 1];
    const int t = threadIdx.x;
    for (int i = t; i < F * OUTC; i += 256)
        wls[i / OUTC][i % OUTC] = Wc[i];
    __syncthreads();

    const int wave = t >> 6, lane = t & 63;
    const int n = blockIdx.x * 4 + wave;
    if (n >= N_NODES) return;

    float v[4];
#pragma unroll
    for (int j = 0; j < 4; j++)
        v[j] = Hb[(size_t)n * F + j * 64 + lane];

    float acc[OUTC];
#pragma unroll
    for (int o = 0; o < OUTC; o++) acc[o] = 0.f;
#pragma unroll
    for (int j = 0; j < 4; j++)
#pragma unroll
        for (int o = 0; o < OUTC; o++)
            acc[o] += v[j] * wls[j * 64 + lane][o];

#pragma unroll
    for (int off = 32; off > 0; off >>= 1)
#pragma unroll
        for (int o = 0; o < OUTC; o++)
            acc[o] += __shfl_xor(acc[o], off, 64);

    if (lane == 0) {
#pragma unroll
        for (int o = 0; o < OUTC; o++)
            out[(size_t)n * OUTC + o] = acc[o] + bc[o];
    }
}

extern "C" void kernel_launch(void* const* d_in, const int* in_sizes, int n_in,
                              void* d_out, int out_size, void* d_ws, size_t ws_size,
                              hipStream_t stream)
{
    const float* x   = (const float*)d_in[0];
    const int*   ei  = (const int*)d_in[1];
    const float* W1  = (const float*)d_in[2];
    const float* as1 = (const float*)d_in[3];
    const float* ad1 = (const float*)d_in[4];
    const float* b1  = (const float*)d_in[5];
    const float* W2  = (const float*)d_in[6];
    const float* as2 = (const float*)d_in[7];
    const float* ad2 = (const float*)d_in[8];
    const float* b2  = (const float*)d_in[9];
    const float* g1  = (const float*)d_in[10];
    const float* be1 = (const float*)d_in[11];
    const float* g2  = (const float*)d_in[12];
    const float* be2 = (const float*)d_in[13];
    const float* Wc  = (const float*)d_in[14];
    const float* bc  = (const float*)d_in[15];
    float* out = (float*)d_out;

    float* ws   = (float*)d_ws;
    float* xw   = ws;                               // N*F
    float* hb   = xw + (size_t)N_NODES * F;         // N*F
    float* Sv   = hb + (size_t)N_NODES * F;         // N*H
    float* Dv   = Sv + (size_t)N_NODES * HEADS;     // N*H
    float* st   = Dv + (size_t)N_NODES * HEADS;     // 2*F
    int*   deg  = (int*)(st + 2 * F);               // N (also used as cursor)
    int*   rowp = deg + N_NODES;                    // N+1
    int*   esrc = rowp + N_NODES + 1;               // E2

    const int grid_e  = (E2 + 255) / 256;
    const int grid_ag = (N_NODES * 64 + 255) / 256;

    // ---- CSR build (edge index is shared by both layers) ----
    hipMemsetAsync(deg, 0, (size_t)N_NODES * 4, stream);
    count_deg<<<grid_e, 256, 0, stream>>>(ei, deg);
    scan_deg<<<1, SCAN_T, 0, stream>>>(deg, rowp);
    hipMemsetAsync(deg, 0, (size_t)N_NODES * 4, stream);
    scatter_edges<<<grid_e, 256, 0, stream>>>(ei, rowp, deg, esrc);

    // ---- layer 1 ----
    gemm_sd<128, 8, 32><<<N_NODES / 8, 256, 0, stream>>>(x, W1, as1, ad1, xw, Sv, Dv);
    gat_aggregate<<<grid_ag, 256, 0, stream>>>(rowp, esrc, Sv, Dv, xw, hb);
    hipMemsetAsync(st, 0, 2 * F * 4, stream);
    bias_relu_stats<<<512, 256, 0, stream>>>(hb, b1, st);
    bn_apply<<<512, 256, 0, stream>>>(hb, st, g1, be1);

    // ---- layer 2 ----
    gemm_sd<256, 8, 32><<<N_NODES / 8, 256, 0, stream>>>(hb, W2, as2, ad2, xw, Sv, Dv);
    gat_aggregate<<<grid_ag, 256, 0, stream>>>(rowp, esrc, Sv, Dv, xw, hb);
    hipMemsetAsync(st, 0, 2 * F * 4, stream);
    bias_relu_stats<<<512, 256, 0, stream>>>(hb, b2, st);
    bn_apply<<<512, 256, 0, stream>>>(hb, st, g2, be2);

    // ---- classifier ----
    classifier<<<(N_NODES + 3) / 4, 256, 0, stream>>>(hb, Wc, bc, out);
}

// Round 4
// 761.727 us; speedup vs baseline: 16.1266x; 1.8182x over previous
//
#include <hip/hip_runtime.h>

#define N_NODES 50000
#define E_EDGES 1600000
#define E2 (E_EDGES + N_NODES)   // 1,650,000 with self loops
#define HEADS 4
#define F 256
#define OUTC 10
#define BN_EPS 1e-5f
#define NEG_SLOPE 0.2f
#define SCAN_T 1024
#define SCAN_CHUNK ((N_NODES + SCAN_T - 1) / SCAN_T)
#define STATB 512                // partial-stats blocks

typedef __attribute__((ext_vector_type(8))) short short8;
typedef __attribute__((ext_vector_type(4))) float f32x4;

__device__ __forceinline__ unsigned short f2bf(float f) {
    unsigned int u = __float_as_uint(f);
    unsigned int r = (u + 0x7fffu + ((u >> 16) & 1u)) >> 16;
    return (unsigned short)r;
}
__device__ __forceinline__ float bf2f(unsigned short b) {
    return __uint_as_float(((unsigned int)b) << 16);
}

// ---------------- convert X f32 -> bf16 ----------------
__global__ __launch_bounds__(256) void convert_x(
    const float* __restrict__ X, unsigned short* __restrict__ Xb)
{
    int i = blockIdx.x * blockDim.x + threadIdx.x;          // float4 index
    const int total = N_NODES * 128 / 4;
    if (i >= total) return;
    float4 v = reinterpret_cast<const float4*>(X)[i];
    ushort4 o = { f2bf(v.x), f2bf(v.y), f2bf(v.z), f2bf(v.w) };
    reinterpret_cast<ushort4*>(Xb)[i] = o;
}

// ---------------- convert W1 [128,256] f32 -> WT1b [256,128] bf16 ------
__global__ __launch_bounds__(256) void convert_w1T(
    const float* __restrict__ W1, unsigned short* __restrict__ WT)
{
    const int t = threadIdx.x;   // output row n
    for (int k = 0; k < 128; k++)
        WT[t * 128 + k] = f2bf(W1[k * 256 + t]);
}

// ---------------- CSR build (integer atomics only) ----------------
__global__ __launch_bounds__(256) void count_deg(
    const int* __restrict__ eidx, int* __restrict__ deg)
{
    int e = blockIdx.x * blockDim.x + threadIdx.x;
    if (e >= E2) return;
    int dst = (e < E_EDGES) ? eidx[E_EDGES + e] : e - E_EDGES;
    atomicAdd(&deg[dst], 1);
}

__global__ __launch_bounds__(SCAN_T) void scan_deg(
    const int* __restrict__ deg, int* __restrict__ rowptr)
{
    __shared__ int part[SCAN_T];
    const int t = threadIdx.x;
    const int base = t * SCAN_CHUNK;
    int s = 0;
    for (int i = 0; i < SCAN_CHUNK; i++) {
        int idx = base + i;
        if (idx < N_NODES) s += deg[idx];
    }
    part[t] = s;
    __syncthreads();
    for (int off = 1; off < SCAN_T; off <<= 1) {
        int v = (t >= off) ? part[t - off] : 0;
        __syncthreads();
        part[t] += v;
        __syncthreads();
    }
    int run = (t == 0) ? 0 : part[t - 1];
    for (int i = 0; i < SCAN_CHUNK; i++) {
        int idx = base + i;
        if (idx < N_NODES) { rowptr[idx] = run; run += deg[idx]; }
    }
    if (t == 0) rowptr[N_NODES] = part[SCAN_T - 1];
}

__global__ __launch_bounds__(256) void scatter_edges(
    const int* __restrict__ eidx, const int* __restrict__ rowptr,
    int* __restrict__ cursor, int* __restrict__ esrc)
{
    int e = blockIdx.x * blockDim.x + threadIdx.x;
    if (e >= E2) return;
    int src, dst;
    if (e < E_EDGES) { src = eidx[e]; dst = eidx[E_EDGES + e]; }
    else             { src = dst = e - E_EDGES; }
    int pos = atomicAdd(&cursor[dst], 1);
    esrc[rowptr[dst] + pos] = src;
}

// ---------------- MFMA GEMM: C[M,256] = A[M,K] @ BT[256,K]^T (+brow) ---
// Block: 4 waves, 64-row tile; wave w -> cols w*64..+63. A-row loads are
// CLAMPED to N_NODES-1 (never read unwritten ws bytes); C writes guarded.
template<int K, bool BROW>
__global__ __launch_bounds__(256) void gemm_mfma(
    const unsigned short* __restrict__ A, const unsigned short* __restrict__ BT,
    const float* __restrict__ brow, unsigned short* __restrict__ C)
{
    const int t = threadIdx.x;
    const int wave = t >> 6, lane = t & 63;
    const int lo = lane & 15, hi = lane >> 4;
    const int row0 = blockIdx.x * 64;
    const int nbase = wave * 64;

    int arow[4];
#pragma unroll
    for (int m = 0; m < 4; m++)
        arow[m] = min(row0 + m * 16 + lo, N_NODES - 1);

    f32x4 acc[4][4];
#pragma unroll
    for (int m = 0; m < 4; m++)
#pragma unroll
        for (int n = 0; n < 4; n++)
            acc[m][n] = (f32x4){0.f, 0.f, 0.f, 0.f};

    for (int k0 = 0; k0 < K; k0 += 32) {
        const int kk = k0 + hi * 8;
        short8 af[4], bfr[4];
#pragma unroll
        for (int m = 0; m < 4; m++)
            af[m] = *reinterpret_cast<const short8*>(
                A + (size_t)arow[m] * K + kk);
#pragma unroll
        for (int n = 0; n < 4; n++)
            bfr[n] = *reinterpret_cast<const short8*>(
                BT + (size_t)(nbase + n * 16 + lo) * K + kk);
#pragma unroll
        for (int m = 0; m < 4; m++)
#pragma unroll
            for (int n = 0; n < 4; n++)
                acc[m][n] = __builtin_amdgcn_mfma_f32_16x16x32_bf16(
                    af[m], bfr[n], acc[m][n], 0, 0, 0);
    }

    float bb[4];
#pragma unroll
    for (int n = 0; n < 4; n++)
        bb[n] = BROW ? brow[nbase + n * 16 + lo] : 0.f;

#pragma unroll
    for (int m = 0; m < 4; m++) {
#pragma unroll
        for (int i = 0; i < 4; i++) {
            int row = row0 + m * 16 + hi * 4 + i;
            if (row < N_NODES) {
#pragma unroll
                for (int n = 0; n < 4; n++) {
                    int col = nbase + n * 16 + lo;
                    C[(size_t)row * F + col] = f2bf(acc[m][n][i] + bb[n]);
                }
            }
        }
    }
}

// ---------------- S/D from XWb ----------------
__global__ __launch_bounds__(256) void sd_kernel(
    const unsigned short* __restrict__ XWb, const float* __restrict__ a_src,
    const float* __restrict__ a_dst, float* __restrict__ S, float* __restrict__ D)
{
    const int wave = threadIdx.x >> 6, lane = threadIdx.x & 63;
    const int n = blockIdx.x * 4 + wave;
    if (n >= N_NODES) return;
    ushort4 xv = *reinterpret_cast<const ushort4*>(XWb + (size_t)n * F + lane * 4);
    float4 as = *reinterpret_cast<const float4*>(a_src + lane * 4);
    float4 ad = *reinterpret_cast<const float4*>(a_dst + lane * 4);
    float x0 = bf2f(xv.x), x1 = bf2f(xv.y), x2 = bf2f(xv.z), x3 = bf2f(xv.w);
    float ps = x0 * as.x + x1 * as.y + x2 * as.z + x3 * as.w;
    float pd = x0 * ad.x + x1 * ad.y + x2 * ad.z + x3 * ad.w;
#pragma unroll
    for (int off = 1; off < 16; off <<= 1) {
        ps += __shfl_xor(ps, off, 64);
        pd += __shfl_xor(pd, off, 64);
    }
    if ((lane & 15) == 0) {
        S[n * HEADS + (lane >> 4)] = ps;
        D[n * HEADS + (lane >> 4)] = pd;
    }
}

// ---------------- fused softmax + aggregation + bias + ReLU ----------
__global__ __launch_bounds__(256) void gat_aggregate(
    const int* __restrict__ rowptr, const int* __restrict__ esrc,
    const float* __restrict__ S, const float* __restrict__ D,
    const unsigned short* __restrict__ XWb, const float* __restrict__ bias,
    unsigned short* __restrict__ Hb)
{
    const int wave = (blockIdx.x * blockDim.x + threadIdx.x) >> 6;
    const int lane = threadIdx.x & 63;
    if (wave >= N_NODES) return;
    const int dst = wave;
    const int beg = rowptr[dst], end = rowptr[dst + 1];
    const int h = lane >> 4;
    const float dh = D[dst * HEADS + h];

    float ax = 0.f, ay = 0.f, az = 0.f, aw = 0.f, den = 0.f;

    for (int i = beg; i < end; i += 64) {
        const int nb = min(64, end - i);
        int mysrc = (i + lane < end) ? esrc[i + lane] : 0;
        for (int j = 0; j < nb; j++) {
            int src = __shfl(mysrc, j, 64);
            float z = S[src * HEADS + h] + dh;
            float a = z > 0.f ? z : NEG_SLOPE * z;
            float w = __expf(a);
            ushort4 xv = *reinterpret_cast<const ushort4*>(
                XWb + (size_t)src * F + lane * 4);
            ax += w * bf2f(xv.x); ay += w * bf2f(xv.y);
            az += w * bf2f(xv.z); aw += w * bf2f(xv.w);
            den += w;
        }
    }
    const float inv = 1.f / (den + 1e-16f);
    float4 bv = *reinterpret_cast<const float4*>(bias + lane * 4);
    float v0 = ax * inv + bv.x, v1 = ay * inv + bv.y;
    float v2 = az * inv + bv.z, v3 = aw * inv + bv.w;
    v0 = v0 > 0.f ? v0 : 0.f; v1 = v1 > 0.f ? v1 : 0.f;
    v2 = v2 > 0.f ? v2 : 0.f; v3 = v3 > 0.f ? v3 : 0.f;
    ushort4 o = { f2bf(v0), f2bf(v1), f2bf(v2), f2bf(v3) };
    *reinterpret_cast<ushort4*>(Hb + (size_t)dst * F + lane * 4) = o;
}

// ---------------- per-channel stats: deterministic two-phase ----------
__global__ __launch_bounds__(256) void stats_partial(
    const unsigned short* __restrict__ Hb, float* __restrict__ pst)
{
    const int t = threadIdx.x;           // channel
    float s = 0.f, sq = 0.f;
    for (int n = blockIdx.x; n < N_NODES; n += STATB) {
        float v = bf2f(Hb[(size_t)n * F + t]);
        s += v; sq += v * v;
    }
    pst[(size_t)(blockIdx.x * 2 + 0) * F + t] = s;
    pst[(size_t)(blockIdx.x * 2 + 1) * F + t] = sq;
}

__global__ __launch_bounds__(512) void stats_reduce(
    const float* __restrict__ pst, float* __restrict__ st)
{
    const int t = threadIdx.x;           // t = kind*256 + channel
    const int kind = t >> 8, c = t & 255;
    float s = 0.f;
    for (int b = 0; b < STATB; b++)      // fixed order -> deterministic
        s += pst[(size_t)(b * 2 + kind) * F + c];
    st[t] = s;
}

// ---------------- BN scale/shift per channel ----------------
__global__ __launch_bounds__(256) void prep_bn(
    const float* __restrict__ st, const float* __restrict__ g,
    const float* __restrict__ be, float* __restrict__ scb,
    float* __restrict__ shb)
{
    const int k = threadIdx.x;
    const float inv_n = 1.f / (float)N_NODES;
    float mu = st[k] * inv_n;
    float var = st[F + k] * inv_n - mu * mu;
    float sc = rsqrtf(var + BN_EPS) * g[k];
    scb[k] = sc;
    shb[k] = be[k] - mu * sc;
}

// ---------------- fold BN1 into W2 (transposed bf16) ----------------
__global__ __launch_bounds__(256) void fold_w2(
    const float* __restrict__ W2, const float* __restrict__ scb,
    unsigned short* __restrict__ WT2b)
{
    const int t = threadIdx.x;       // n
    const int k0 = blockIdx.x * 8;
#pragma unroll
    for (int kk = 0; kk < 8; kk++)
        WT2b[(size_t)t * F + k0 + kk] = f2bf(W2[(size_t)(k0 + kk) * F + t] * scb[k0 + kk]);
}

// brow[n] = sum_k shb[k] * W2[k,n]   (one thread per n, fixed order)
__global__ __launch_bounds__(256) void brow_kernel(
    const float* __restrict__ W2, const float* __restrict__ shb,
    float* __restrict__ brow)
{
    const int n = threadIdx.x;
    float acc = 0.f;
    for (int k = 0; k < F; k++)
        acc += shb[k] * W2[(size_t)k * F + n];
    brow[n] = acc;
}

// ---------------- fold BN2 into classifier weights ----------------
__global__ __launch_bounds__(256) void fold_wc(
    const float* __restrict__ Wc, const float* __restrict__ bc,
    const float* __restrict__ scb, const float* __restrict__ shb,
    float* __restrict__ Wcp, float* __restrict__ bcp)
{
    const int k = threadIdx.x;
    const float sc = scb[k];
#pragma unroll
    for (int o = 0; o < OUTC; o++)
        Wcp[k * OUTC + o] = Wc[k * OUTC + o] * sc;
    if (k < OUTC) {
        float acc = bc[k];
        for (int kk = 0; kk < F; kk++)
            acc += shb[kk] * Wc[kk * OUTC + k];
        bcp[k] = acc;
    }
}

// ---------------- classifier: [N,256]bf16 @ Wcp[256,10] + bcp --------
__global__ __launch_bounds__(256) void classifier(
    const unsigned short* __restrict__ Hb, const float* __restrict__ Wcp,
    const float* __restrict__ bcp, float* __restrict__ out)
{
    __shared__ float wls[F][OUTC + 1];
    const int t = threadIdx.x;
    for (int i = t; i < F * OUTC; i += 256)
        wls[i / OUTC][i % OUTC] = Wcp[i];
    __syncthreads();

    const int wave = t >> 6, lane = t & 63;
    const int n = blockIdx.x * 4 + wave;
    if (n >= N_NODES) return;

    float v[4];
#pragma unroll
    for (int j = 0; j < 4; j++)
        v[j] = bf2f(Hb[(size_t)n * F + j * 64 + lane]);

    float acc[OUTC];
#pragma unroll
    for (int o = 0; o < OUTC; o++) acc[o] = 0.f;
#pragma unroll
    for (int j = 0; j < 4; j++)
#pragma unroll
        for (int o = 0; o < OUTC; o++)
            acc[o] += v[j] * wls[j * 64 + lane][o];

#pragma unroll
    for (int off = 32; off > 0; off >>= 1)
#pragma unroll
        for (int o = 0; o < OUTC; o++)
            acc[o] += __shfl_xor(acc[o], off, 64);

    if (lane == 0) {
#pragma unroll
        for (int o = 0; o < OUTC; o++)
            out[(size_t)n * OUTC + o] = acc[o] + bcp[o];
    }
}

extern "C" void kernel_launch(void* const* d_in, const int* in_sizes, int n_in,
                              void* d_out, int out_size, void* d_ws, size_t ws_size,
                              hipStream_t stream)
{
    const float* x   = (const float*)d_in[0];
    const int*   ei  = (const int*)d_in[1];
    const float* W1  = (const float*)d_in[2];
    const float* as1 = (const float*)d_in[3];
    const float* ad1 = (const float*)d_in[4];
    const float* b1  = (const float*)d_in[5];
    const float* W2  = (const float*)d_in[6];
    const float* as2 = (const float*)d_in[7];
    const float* ad2 = (const float*)d_in[8];
    const float* b2  = (const float*)d_in[9];
    const float* g1  = (const float*)d_in[10];
    const float* be1 = (const float*)d_in[11];
    const float* g2  = (const float*)d_in[12];
    const float* be2 = (const float*)d_in[13];
    const float* Wc  = (const float*)d_in[14];
    const float* bc  = (const float*)d_in[15];
    float* out = (float*)d_out;

    char* w = (char*)d_ws;
    unsigned short* Xb   = (unsigned short*)w;   w += (size_t)N_NODES * 128 * 2;
    unsigned short* XWb  = (unsigned short*)w;   w += (size_t)N_NODES * F * 2;
    unsigned short* Hb   = (unsigned short*)w;   w += (size_t)N_NODES * F * 2;
    unsigned short* WT1b = (unsigned short*)w;   w += 256 * 128 * 2;
    unsigned short* WT2b = (unsigned short*)w;   w += 256 * 256 * 2;
    float* Wcp   = (float*)w;                    w += F * OUTC * 4;
    float* bcp   = (float*)w;                    w += 64;
    float* brow2 = (float*)w;                    w += F * 4;
    float* scb   = (float*)w;                    w += F * 4;
    float* shb   = (float*)w;                    w += F * 4;
    float* Sv    = (float*)w;                    w += (size_t)N_NODES * HEADS * 4;
    float* Dv    = (float*)w;                    w += (size_t)N_NODES * HEADS * 4;
    float* st    = (float*)w;                    w += 2 * F * 4;
    float* pst   = (float*)w;                    w += (size_t)STATB * 2 * F * 4;
    int* deg     = (int*)w;                      w += (size_t)N_NODES * 4;
    int* rowp    = (int*)w;                      w += (size_t)(N_NODES + 1) * 4;
    int* esrc    = (int*)w;                      /* E2 ints */

    const int grid_e    = (E2 + 255) / 256;
    const int grid_nw   = (N_NODES + 3) / 4;
    const int grid_gemm = (N_NODES + 63) / 64;   // 782

    // ---- prep ----
    convert_x<<<(N_NODES * 128 / 4 + 255) / 256, 256, 0, stream>>>(x, Xb);
    convert_w1T<<<1, 256, 0, stream>>>(W1, WT1b);
    hipMemsetAsync(deg, 0, (size_t)N_NODES * 4, stream);
    count_deg<<<grid_e, 256, 0, stream>>>(ei, deg);
    scan_deg<<<1, SCAN_T, 0, stream>>>(deg, rowp);
    hipMemsetAsync(deg, 0, (size_t)N_NODES * 4, stream);
    scatter_edges<<<grid_e, 256, 0, stream>>>(ei, rowp, deg, esrc);

    // ---- layer 1 ----
    gemm_mfma<128, false><<<grid_gemm, 256, 0, stream>>>(Xb, WT1b, nullptr, XWb);
    sd_kernel<<<grid_nw, 256, 0, stream>>>(XWb, as1, ad1, Sv, Dv);
    gat_aggregate<<<grid_nw, 256, 0, stream>>>(rowp, esrc, Sv, Dv, XWb, b1, Hb);
    stats_partial<<<STATB, 256, 0, stream>>>(Hb, pst);
    stats_reduce<<<1, 512, 0, stream>>>(pst, st);
    prep_bn<<<1, 256, 0, stream>>>(st, g1, be1, scb, shb);
    fold_w2<<<32, 256, 0, stream>>>(W2, scb, WT2b);
    brow_kernel<<<1, 256, 0, stream>>>(W2, shb, brow2);

    // ---- layer 2 ----
    gemm_mfma<256, true><<<grid_gemm, 256, 0, stream>>>(Hb, WT2b, brow2, XWb);
    sd_kernel<<<grid_nw, 256, 0, stream>>>(XWb, as2, ad2, Sv, Dv);
    gat_aggregate<<<grid_nw, 256, 0, stream>>>(rowp, esrc, Sv, Dv, XWb, b2, Hb);
    stats_partial<<<STATB, 256, 0, stream>>>(Hb, pst);
    stats_reduce<<<1, 512, 0, stream>>>(pst, st);
    prep_bn<<<1, 256, 0, stream>>>(st, g2, be2, scb, shb);
    fold_wc<<<1, 256, 0, stream>>>(Wc, bc, scb, shb, Wcp, bcp);

    // ---- classifier ----
    classifier<<<grid_nw, 256, 0, stream>>>(Hb, Wcp, bcp, out);
}

// Round 6
// 659.308 us; speedup vs baseline: 18.6318x; 1.1553x over previous
//
#include <hip/hip_runtime.h>

#define N_NODES 50000
#define E_EDGES 1600000
#define E2 (E_EDGES + N_NODES)   // 1,650,000 with self loops
#define HEADS 4
#define F 256
#define OUTC 10
#define BN_EPS 1e-5f
#define NEG_SLOPE 0.2f
#define STATB 512                // partial-stats blocks
#define SB 1024                  // scan block size
#define NB ((N_NODES + SB - 1) / SB)   // 49 scan blocks

typedef __attribute__((ext_vector_type(8))) short short8;
typedef __attribute__((ext_vector_type(4))) float f32x4;

__device__ __forceinline__ unsigned short f2bf(float f) {
    unsigned int u = __float_as_uint(f);
    unsigned int r = (u + 0x7fffu + ((u >> 16) & 1u)) >> 16;
    return (unsigned short)r;
}
__device__ __forceinline__ float bf2f(unsigned short b) {
    return __uint_as_float(((unsigned int)b) << 16);
}

// ---------------- convert X f32 -> bf16 ----------------
__global__ __launch_bounds__(256) void convert_x(
    const float* __restrict__ X, unsigned short* __restrict__ Xb)
{
    int i = blockIdx.x * blockDim.x + threadIdx.x;          // float4 index
    const int total = N_NODES * 128 / 4;
    if (i >= total) return;
    float4 v = reinterpret_cast<const float4*>(X)[i];
    ushort4 o = { f2bf(v.x), f2bf(v.y), f2bf(v.z), f2bf(v.w) };
    reinterpret_cast<ushort4*>(Xb)[i] = o;
}

// ---------------- convert W1 [128,256] f32 -> WT1b [256,128] bf16 ------
__global__ __launch_bounds__(256) void convert_w1T(
    const float* __restrict__ W1, unsigned short* __restrict__ WT)
{
    const int k = blockIdx.x;        // 128 blocks
    const int n = threadIdx.x;       // 256 threads, coalesced read
    WT[n * 128 + k] = f2bf(W1[k * 256 + n]);
}

// ---------------- CSR build (integer atomics only) ----------------
__global__ __launch_bounds__(256) void count_deg(
    const int* __restrict__ eidx, int* __restrict__ deg)
{
    int e = blockIdx.x * blockDim.x + threadIdx.x;
    if (e >= E2) return;
    int dst = (e < E_EDGES) ? eidx[E_EDGES + e] : e - E_EDGES;
    atomicAdd(&deg[dst], 1);
}

// parallel exclusive scan: per-block scan + block sums
__global__ __launch_bounds__(SB) void scan_blocks(
    const int* __restrict__ deg, int* __restrict__ rowptr, int* __restrict__ bsum)
{
    __shared__ int sm[SB];
    const int t = threadIdx.x;
    const int idx = blockIdx.x * SB + t;
    int v = (idx < N_NODES) ? deg[idx] : 0;
    sm[t] = v;
    __syncthreads();
    for (int off = 1; off < SB; off <<= 1) {
        int u = (t >= off) ? sm[t - off] : 0;
        __syncthreads();
        sm[t] += u;
        __syncthreads();
    }
    if (idx < N_NODES) rowptr[idx] = sm[t] - v;   // exclusive within block
    if (t == SB - 1) bsum[blockIdx.x] = sm[t];
}

__global__ __launch_bounds__(64) void scan_bsums(
    const int* __restrict__ bsum, int* __restrict__ boff, int* __restrict__ rowptr)
{
    if (threadIdx.x == 0) {
        int run = 0;
        for (int b = 0; b < NB; b++) { boff[b] = run; run += bsum[b]; }
        rowptr[N_NODES] = run;
    }
}

__global__ __launch_bounds__(SB) void scan_add(
    int* __restrict__ rowptr, const int* __restrict__ boff)
{
    const int idx = blockIdx.x * SB + threadIdx.x;
    if (idx < N_NODES) rowptr[idx] += boff[blockIdx.x];
}

__global__ __launch_bounds__(256) void scatter_edges(
    const int* __restrict__ eidx, const int* __restrict__ rowptr,
    int* __restrict__ cursor, int* __restrict__ esrc)
{
    int e = blockIdx.x * blockDim.x + threadIdx.x;
    if (e >= E2) return;
    int src, dst;
    if (e < E_EDGES) { src = eidx[e]; dst = eidx[E_EDGES + e]; }
    else             { src = dst = e - E_EDGES; }
    int pos = atomicAdd(&cursor[dst], 1);
    esrc[rowptr[dst] + pos] = src;
}

// ---------------- MFMA GEMM: C[M,256] = A[M,K] @ BT[256,K]^T (+brow) ---
template<int K, bool BROW>
__global__ __launch_bounds__(256) void gemm_mfma(
    const unsigned short* __restrict__ A, const unsigned short* __restrict__ BT,
    const float* __restrict__ brow, unsigned short* __restrict__ C)
{
    const int t = threadIdx.x;
    const int wave = t >> 6, lane = t & 63;
    const int lo = lane & 15, hi = lane >> 4;
    const int row0 = blockIdx.x * 64;
    const int nbase = wave * 64;

    int arow[4];
#pragma unroll
    for (int m = 0; m < 4; m++)
        arow[m] = min(row0 + m * 16 + lo, N_NODES - 1);   // never read unwritten ws

    f32x4 acc[4][4];
#pragma unroll
    for (int m = 0; m < 4; m++)
#pragma unroll
        for (int n = 0; n < 4; n++)
            acc[m][n] = (f32x4){0.f, 0.f, 0.f, 0.f};

    for (int k0 = 0; k0 < K; k0 += 32) {
        const int kk = k0 + hi * 8;
        short8 af[4], bfr[4];
#pragma unroll
        for (int m = 0; m < 4; m++)
            af[m] = *reinterpret_cast<const short8*>(
                A + (size_t)arow[m] * K + kk);
#pragma unroll
        for (int n = 0; n < 4; n++)
            bfr[n] = *reinterpret_cast<const short8*>(
                BT + (size_t)(nbase + n * 16 + lo) * K + kk);
#pragma unroll
        for (int m = 0; m < 4; m++)
#pragma unroll
            for (int n = 0; n < 4; n++)
                acc[m][n] = __builtin_amdgcn_mfma_f32_16x16x32_bf16(
                    af[m], bfr[n], acc[m][n], 0, 0, 0);
    }

    float bb[4];
#pragma unroll
    for (int n = 0; n < 4; n++)
        bb[n] = BROW ? brow[nbase + n * 16 + lo] : 0.f;

#pragma unroll
    for (int m = 0; m < 4; m++) {
#pragma unroll
        for (int i = 0; i < 4; i++) {
            int row = row0 + m * 16 + hi * 4 + i;
            if (row < N_NODES) {
#pragma unroll
                for (int n = 0; n < 4; n++) {
                    int col = nbase + n * 16 + lo;
                    C[(size_t)row * F + col] = f2bf(acc[m][n][i] + bb[n]);
                }
            }
        }
    }
}

// ---------------- S/D from XWb ----------------
__global__ __launch_bounds__(256) void sd_kernel(
    const unsigned short* __restrict__ XWb, const float* __restrict__ a_src,
    const float* __restrict__ a_dst, float* __restrict__ S, float* __restrict__ D)
{
    const int wave = threadIdx.x >> 6, lane = threadIdx.x & 63;
    const int n = blockIdx.x * 4 + wave;
    if (n >= N_NODES) return;
    ushort4 xv = *reinterpret_cast<const ushort4*>(XWb + (size_t)n * F + lane * 4);
    float4 as = *reinterpret_cast<const float4*>(a_src + lane * 4);
    float4 ad = *reinterpret_cast<const float4*>(a_dst + lane * 4);
    float x0 = bf2f(xv.x), x1 = bf2f(xv.y), x2 = bf2f(xv.z), x3 = bf2f(xv.w);
    float ps = x0 * as.x + x1 * as.y + x2 * as.z + x3 * as.w;
    float pd = x0 * ad.x + x1 * ad.y + x2 * ad.z + x3 * ad.w;
#pragma unroll
    for (int off = 1; off < 16; off <<= 1) {
        ps += __shfl_xor(ps, off, 64);
        pd += __shfl_xor(pd, off, 64);
    }
    if ((lane & 15) == 0) {
        S[n * HEADS + (lane >> 4)] = ps;
        D[n * HEADS + (lane >> 4)] = pd;
    }
}

// ------- fused softmax + aggregation + bias + ReLU (LDS-staged w) -----
// Chunk of <=64 edges: lane j computes the 4 head-weights for ITS edge
// (4 exps/edge-chunk-lane vs 64 in the naive form) and stages (src, w4)
// in per-wave LDS. Inner loop: sbuf[j] is a 64-lane broadcast read;
// wbuf[j][h] gives each lane the weight for ITS OWN head (the R5 shfl
// version broadcast the SOURCE lane's head — that was the bug).
// No __syncthreads: buffers are per-wave, LDS RAW ordered within a wave.
__global__ __launch_bounds__(256) void gat_aggregate(
    const int* __restrict__ rowptr, const int* __restrict__ esrc,
    const float* __restrict__ S, const float* __restrict__ D,
    const unsigned short* __restrict__ XWb, const float* __restrict__ bias,
    unsigned short* __restrict__ Hb)
{
    __shared__ int   sbuf[4][64];
    __shared__ float wbuf[4][64][4];
    const int wv   = threadIdx.x >> 6;
    const int lane = threadIdx.x & 63;
    const int dst  = blockIdx.x * 4 + wv;
    if (dst >= N_NODES) return;
    const int beg = rowptr[dst], end = rowptr[dst + 1];
    const int h = lane >> 4;
    const float4 d4 = *reinterpret_cast<const float4*>(D + dst * HEADS);

    float ax = 0.f, ay = 0.f, az = 0.f, aw = 0.f, den = 0.f;

    for (int i = beg; i < end; i += 64) {
        const int nb = min(64, end - i);
        const int mysrc = (i + lane < end) ? esrc[i + lane] : 0;   // S[0] is valid
        const float4 s4 = *reinterpret_cast<const float4*>(S + mysrc * HEADS);
        float4 w4; float z;
        z = s4.x + d4.x; w4.x = __expf(z > 0.f ? z : NEG_SLOPE * z);
        z = s4.y + d4.y; w4.y = __expf(z > 0.f ? z : NEG_SLOPE * z);
        z = s4.z + d4.z; w4.z = __expf(z > 0.f ? z : NEG_SLOPE * z);
        z = s4.w + d4.w; w4.w = __expf(z > 0.f ? z : NEG_SLOPE * z);
        sbuf[wv][lane] = mysrc;
        *reinterpret_cast<float4*>(&wbuf[wv][lane][0]) = w4;

        int j = 0;
        for (; j + 7 < nb; j += 8) {
            int s0 = sbuf[wv][j + 0], s1 = sbuf[wv][j + 1];
            int s2 = sbuf[wv][j + 2], s3 = sbuf[wv][j + 3];
            int s4i = sbuf[wv][j + 4], s5 = sbuf[wv][j + 5];
            int s6 = sbuf[wv][j + 6], s7 = sbuf[wv][j + 7];
            float w0 = wbuf[wv][j + 0][h], w1 = wbuf[wv][j + 1][h];
            float w2 = wbuf[wv][j + 2][h], w3 = wbuf[wv][j + 3][h];
            float w4f = wbuf[wv][j + 4][h], w5 = wbuf[wv][j + 5][h];
            float w6 = wbuf[wv][j + 6][h], w7 = wbuf[wv][j + 7][h];
            ushort4 x0 = *reinterpret_cast<const ushort4*>(XWb + (size_t)s0 * F + lane * 4);
            ushort4 x1 = *reinterpret_cast<const ushort4*>(XWb + (size_t)s1 * F + lane * 4);
            ushort4 x2 = *reinterpret_cast<const ushort4*>(XWb + (size_t)s2 * F + lane * 4);
            ushort4 x3 = *reinterpret_cast<const ushort4*>(XWb + (size_t)s3 * F + lane * 4);
            ushort4 x4 = *reinterpret_cast<const ushort4*>(XWb + (size_t)s4i * F + lane * 4);
            ushort4 x5 = *reinterpret_cast<const ushort4*>(XWb + (size_t)s5 * F + lane * 4);
            ushort4 x6 = *reinterpret_cast<const ushort4*>(XWb + (size_t)s6 * F + lane * 4);
            ushort4 x7 = *reinterpret_cast<const ushort4*>(XWb + (size_t)s7 * F + lane * 4);
            ax += w0 * bf2f(x0.x) + w1 * bf2f(x1.x) + w2 * bf2f(x2.x) + w3 * bf2f(x3.x)
                + w4f * bf2f(x4.x) + w5 * bf2f(x5.x) + w6 * bf2f(x6.x) + w7 * bf2f(x7.x);
            ay += w0 * bf2f(x0.y) + w1 * bf2f(x1.y) + w2 * bf2f(x2.y) + w3 * bf2f(x3.y)
                + w4f * bf2f(x4.y) + w5 * bf2f(x5.y) + w6 * bf2f(x6.y) + w7 * bf2f(x7.y);
            az += w0 * bf2f(x0.z) + w1 * bf2f(x1.z) + w2 * bf2f(x2.z) + w3 * bf2f(x3.z)
                + w4f * bf2f(x4.z) + w5 * bf2f(x5.z) + w6 * bf2f(x6.z) + w7 * bf2f(x7.z);
            aw += w0 * bf2f(x0.w) + w1 * bf2f(x1.w) + w2 * bf2f(x2.w) + w3 * bf2f(x3.w)
                + w4f * bf2f(x4.w) + w5 * bf2f(x5.w) + w6 * bf2f(x6.w) + w7 * bf2f(x7.w);
            den += ((w0 + w1) + (w2 + w3)) + ((w4f + w5) + (w6 + w7));
        }
        for (; j < nb; j++) {
            int   src = sbuf[wv][j];
            float w   = wbuf[wv][j][h];
            ushort4 xv = *reinterpret_cast<const ushort4*>(XWb + (size_t)src * F + lane * 4);
            ax += w * bf2f(xv.x); ay += w * bf2f(xv.y);
            az += w * bf2f(xv.z); aw += w * bf2f(xv.w);
            den += w;
        }
    }
    const float inv = 1.f / (den + 1e-16f);
    float4 bv = *reinterpret_cast<const float4*>(bias + lane * 4);
    float v0 = ax * inv + bv.x, v1 = ay * inv + bv.y;
    float v2 = az * inv + bv.z, v3 = aw * inv + bv.w;
    v0 = v0 > 0.f ? v0 : 0.f; v1 = v1 > 0.f ? v1 : 0.f;
    v2 = v2 > 0.f ? v2 : 0.f; v3 = v3 > 0.f ? v3 : 0.f;
    ushort4 o = { f2bf(v0), f2bf(v1), f2bf(v2), f2bf(v3) };
    *reinterpret_cast<ushort4*>(Hb + (size_t)dst * F + lane * 4) = o;
}

// ---------------- per-channel stats: deterministic two-phase ----------
__global__ __launch_bounds__(256) void stats_partial(
    const unsigned short* __restrict__ Hb, float* __restrict__ pst)
{
    const int t = threadIdx.x;           // channel
    float s = 0.f, sq = 0.f;
    for (int n = blockIdx.x; n < N_NODES; n += STATB) {
        float v = bf2f(Hb[(size_t)n * F + t]);
        s += v; sq += v * v;
    }
    pst[(size_t)(blockIdx.x * 2 + 0) * F + t] = s;
    pst[(size_t)(blockIdx.x * 2 + 1) * F + t] = sq;
}

__global__ __launch_bounds__(512) void stats_reduce(
    const float* __restrict__ pst, float* __restrict__ st)
{
    const int t = threadIdx.x;           // t = kind*256 + channel
    const int kind = t >> 8, c = t & 255;
    float s = 0.f;
    for (int b = 0; b < STATB; b++)      // fixed order -> deterministic
        s += pst[(size_t)(b * 2 + kind) * F + c];
    st[t] = s;
}

// ---------------- BN scale/shift per channel ----------------
__global__ __launch_bounds__(256) void prep_bn(
    const float* __restrict__ st, const float* __restrict__ g,
    const float* __restrict__ be, float* __restrict__ scb,
    float* __restrict__ shb)
{
    const int k = threadIdx.x;
    const float inv_n = 1.f / (float)N_NODES;
    float mu = st[k] * inv_n;
    float var = st[F + k] * inv_n - mu * mu;
    float sc = rsqrtf(var + BN_EPS) * g[k];
    scb[k] = sc;
    shb[k] = be[k] - mu * sc;
}

// ---------------- fold BN1 into W2 (transposed bf16) ----------------
__global__ __launch_bounds__(256) void fold_w2(
    const float* __restrict__ W2, const float* __restrict__ scb,
    unsigned short* __restrict__ WT2b)
{
    const int t = threadIdx.x;       // n
    const int k0 = blockIdx.x * 8;
#pragma unroll
    for (int kk = 0; kk < 8; kk++)
        WT2b[(size_t)t * F + k0 + kk] = f2bf(W2[(size_t)(k0 + kk) * F + t] * scb[k0 + kk]);
}

// brow[n] = sum_k shb[k] * W2[k,n]   (fixed order -> deterministic)
__global__ __launch_bounds__(256) void brow_kernel(
    const float* __restrict__ W2, const float* __restrict__ shb,
    float* __restrict__ brow)
{
    const int n = threadIdx.x;
    float acc = 0.f;
    for (int k = 0; k < F; k++)
        acc += shb[k] * W2[(size_t)k * F + n];
    brow[n] = acc;
}

// ---------------- fold BN2 into classifier weights ----------------
__global__ __launch_bounds__(256) void fold_wc(
    const float* __restrict__ Wc, const float* __restrict__ bc,
    const float* __restrict__ scb, const float* __restrict__ shb,
    float* __restrict__ Wcp, float* __restrict__ bcp)
{
    const int k = threadIdx.x;
    const float sc = scb[k];
#pragma unroll
    for (int o = 0; o < OUTC; o++)
        Wcp[k * OUTC + o] = Wc[k * OUTC + o] * sc;
    if (k < OUTC) {
        float acc = bc[k];
        for (int kk = 0; kk < F; kk++)
            acc += shb[kk] * Wc[kk * OUTC + k];
        bcp[k] = acc;
    }
}

// ---------------- classifier: [N,256]bf16 @ Wcp[256,10] + bcp --------
__global__ __launch_bounds__(256) void classifier(
    const unsigned short* __restrict__ Hb, const float* __restrict__ Wcp,
    const float* __restrict__ bcp, float* __restrict__ out)
{
    __shared__ float wls[F][OUTC + 1];
    const int t = threadIdx.x;
    for (int i = t; i < F * OUTC; i += 256)
        wls[i / OUTC][i % OUTC] = Wcp[i];
    __syncthreads();

    const int wave = t >> 6, lane = t & 63;
    const int n = blockIdx.x * 4 + wave;
    if (n >= N_NODES) return;

    float v[4];
#pragma unroll
    for (int j = 0; j < 4; j++)
        v[j] = bf2f(Hb[(size_t)n * F + j * 64 + lane]);

    float acc[OUTC];
#pragma unroll
    for (int o = 0; o < OUTC; o++) acc[o] = 0.f;
#pragma unroll
    for (int j = 0; j < 4; j++)
#pragma unroll
        for (int o = 0; o < OUTC; o++)
            acc[o] += v[j] * wls[j * 64 + lane][o];

#pragma unroll
    for (int off = 32; off > 0; off >>= 1)
#pragma unroll
        for (int o = 0; o < OUTC; o++)
            acc[o] += __shfl_xor(acc[o], off, 64);

    if (lane == 0) {
#pragma unroll
        for (int o = 0; o < OUTC; o++)
            out[(size_t)n * OUTC + o] = acc[o] + bcp[o];
    }
}

extern "C" void kernel_launch(void* const* d_in, const int* in_sizes, int n_in,
                              void* d_out, int out_size, void* d_ws, size_t ws_size,
                              hipStream_t stream)
{
    const float* x   = (const float*)d_in[0];
    const int*   ei  = (const int*)d_in[1];
    const float* W1  = (const float*)d_in[2];
    const float* as1 = (const float*)d_in[3];
    const float* ad1 = (const float*)d_in[4];
    const float* b1  = (const float*)d_in[5];
    const float* W2  = (const float*)d_in[6];
    const float* as2 = (const float*)d_in[7];
    const float* ad2 = (const float*)d_in[8];
    const float* b2  = (const float*)d_in[9];
    const float* g1  = (const float*)d_in[10];
    const float* be1 = (const float*)d_in[11];
    const float* g2  = (const float*)d_in[12];
    const float* be2 = (const float*)d_in[13];
    const float* Wc  = (const float*)d_in[14];
    const float* bc  = (const float*)d_in[15];
    float* out = (float*)d_out;

    char* w = (char*)d_ws;
    unsigned short* Xb   = (unsigned short*)w;   w += (size_t)N_NODES * 128 * 2;
    unsigned short* XWb  = (unsigned short*)w;   w += (size_t)N_NODES * F * 2;
    unsigned short* Hb   = (unsigned short*)w;   w += (size_t)N_NODES * F * 2;
    unsigned short* WT1b = (unsigned short*)w;   w += 256 * 128 * 2;
    unsigned short* WT2b = (unsigned short*)w;   w += 256 * 256 * 2;
    float* Wcp   = (float*)w;                    w += F * OUTC * 4;
    float* bcp   = (float*)w;                    w += 64;
    float* brow2 = (float*)w;                    w += F * 4;
    float* scb   = (float*)w;                    w += F * 4;
    float* shb   = (float*)w;                    w += F * 4;
    float* Sv    = (float*)w;                    w += (size_t)N_NODES * HEADS * 4;
    float* Dv    = (float*)w;                    w += (size_t)N_NODES * HEADS * 4;
    float* st    = (float*)w;                    w += 2 * F * 4;
    float* pst   = (float*)w;                    w += (size_t)STATB * 2 * F * 4;
    int* deg     = (int*)w;                      w += (size_t)N_NODES * 4;
    int* rowp    = (int*)w;                      w += (size_t)(N_NODES + 1) * 4;
    int* bsum    = (int*)w;                      w += NB * 4;
    int* boff    = (int*)w;                      w += NB * 4;
    int* esrc    = (int*)w;                      /* E2 ints */

    const int grid_e    = (E2 + 255) / 256;
    const int grid_nw   = (N_NODES + 3) / 4;
    const int grid_gemm = (N_NODES + 63) / 64;   // 782

    // ---- prep ----
    convert_x<<<(N_NODES * 128 / 4 + 255) / 256, 256, 0, stream>>>(x, Xb);
    convert_w1T<<<128, 256, 0, stream>>>(W1, WT1b);
    hipMemsetAsync(deg, 0, (size_t)N_NODES * 4, stream);
    count_deg<<<grid_e, 256, 0, stream>>>(ei, deg);
    scan_blocks<<<NB, SB, 0, stream>>>(deg, rowp, bsum);
    scan_bsums<<<1, 64, 0, stream>>>(bsum, boff, rowp);
    scan_add<<<NB, SB, 0, stream>>>(rowp, boff);
    hipMemsetAsync(deg, 0, (size_t)N_NODES * 4, stream);
    scatter_edges<<<grid_e, 256, 0, stream>>>(ei, rowp, deg, esrc);

    // ---- layer 1 ----
    gemm_mfma<128, false><<<grid_gemm, 256, 0, stream>>>(Xb, WT1b, nullptr, XWb);
    sd_kernel<<<grid_nw, 256, 0, stream>>>(XWb, as1, ad1, Sv, Dv);
    gat_aggregate<<<grid_nw, 256, 0, stream>>>(rowp, esrc, Sv, Dv, XWb, b1, Hb);
    stats_partial<<<STATB, 256, 0, stream>>>(Hb, pst);
    stats_reduce<<<1, 512, 0, stream>>>(pst, st);
    prep_bn<<<1, 256, 0, stream>>>(st, g1, be1, scb, shb);
    fold_w2<<<32, 256, 0, stream>>>(W2, scb, WT2b);
    brow_kernel<<<1, 256, 0, stream>>>(W2, shb, brow2);

    // ---- layer 2 ----
    gemm_mfma<256, true><<<grid_gemm, 256, 0, stream>>>(Hb, WT2b, brow2, XWb);
    sd_kernel<<<grid_nw, 256, 0, stream>>>(XWb, as2, ad2, Sv, Dv);
    gat_aggregate<<<grid_nw, 256, 0, stream>>>(rowp, esrc, Sv, Dv, XWb, b2, Hb);
    stats_partial<<<STATB, 256, 0, stream>>>(Hb, pst);
    stats_reduce<<<1, 512, 0, stream>>>(pst, st);
    prep_bn<<<1, 256, 0, stream>>>(st, g2, be2, scb, shb);
    fold_wc<<<1, 256, 0, stream>>>(Wc, bc, scb, shb, Wcp, bcp);

    // ---- classifier ----
    classifier<<<grid_nw, 256, 0, stream>>>(Hb, Wcp, bcp, out);
}